// Round 1
// baseline (61.333 us; speedup 1.0000x reference)
//
#include <hip/hip_runtime.h>

// ---- problem constants ----
#define IN_C  16
#define OUT_C 32
#define NB 2
#define TT 8
#define DD 8
#define HH 32
#define WW 32
// padded input dims (pad=1 both sides)
#define TP 10
#define DP 10
#define HP 34
#define WP 34
#define TAPS 81           // 3^4
#define WT_TAPS 82        // padded to even (tap 81 = zeros)

#define XT_ELEMS (NB*TP*DP*HP*WP*IN_C)      // 3,699,200 bf16
#define WT_ELEMS (WT_TAPS*OUT_C*IN_C)       // 41,984 bf16

typedef __bf16 bf16x8 __attribute__((ext_vector_type(8)));
typedef float  f32x4  __attribute__((ext_vector_type(4)));

__device__ __forceinline__ unsigned short f2bf(float f) {
    unsigned int u = __builtin_bit_cast(unsigned int, f);
    u += 0x7fffu + ((u >> 16) & 1u);       // RNE
    return (unsigned short)(u >> 16);
}

// tap -> spatial offset in padded xt (elements), compile-time foldable
__device__ __forceinline__ constexpr int tap_off(int tap) {
    int kt = tap / 27, r = tap % 27;
    int kd = r / 9, r2 = r % 9;
    int kh = r2 / 3, kw = r2 % 3;
    return (((kt * DP + kd) * HP + kh) * WP + kw) * IN_C;
}

// ---------------- x: f32 NCHW-ish -> bf16 channel-last, zero-padded ----------------
// block = one (n,t,d,h) row: 512 threads read 16c x 32w coalesced, LDS transpose,
// 256 threads write 1 KiB contiguous (32 pos x 16 c bf16).
__global__ __launch_bounds__(512) void xpose_kernel(const float* __restrict__ x,
                                                    unsigned short* __restrict__ xt) {
    __shared__ unsigned short ls[WW * IN_C];
    int b = blockIdx.x;
    int h = b & 31, d = (b >> 5) & 7, t = (b >> 8) & 7, n = b >> 11;
    int tid = threadIdx.x;
    int c = tid >> 5, w = tid & 31;
    float v = x[((((n * IN_C + c) * TT + t) * DD + d) * HH + h) * WW + w];
    ls[w * IN_C + c] = f2bf(v);
    __syncthreads();
    if (tid < 256) {
        int base = ((((n * TP + (t + 1)) * DP + (d + 1)) * HP + (h + 1)) * WP + 1) * IN_C;
        unsigned int val = (unsigned int)ls[tid * 2] | ((unsigned int)ls[tid * 2 + 1] << 16);
        *reinterpret_cast<unsigned int*>(&xt[base + tid * 2]) = val;
    }
}

// ---------------- weight -> wt[82][OUT_C][IN_C] bf16 (tap 81 zeroed) ----------------
__global__ void wxform_kernel(const float* __restrict__ wsrc,
                              unsigned short* __restrict__ wt) {
    int idx = blockIdx.x * blockDim.x + threadIdx.x;
    if (idx >= WT_ELEMS) return;
    int tap = idx >> 9;            // /(OUT_C*IN_C)=512
    int rem = idx & 511;
    int o = rem >> 4, i = rem & 15;
    float v = (tap < TAPS) ? wsrc[(o * IN_C + i) * TAPS + tap] : 0.0f;
    wt[idx] = f2bf(v);
}

// ---------------- main: implicit GEMM via mfma_f32_16x16x32_bf16 ----------------
// wave = 16 w-positions x 16 oc; 41 MFMAs (2 taps x 16 ic per MFMA).
// A frag: lane holds xt[n][t+kt][d+kd][h+kh][w0+(l&15)+kw][ic0..ic0+7]  (16 B)
// B frag: lane holds wt[tap][oc0+(l&15)][ic0..ic0+7]                    (16 B)
// D: row (= w offset) = 4*(l>>4)+reg, col (= oc) = l&15  -> float4 store, coalesced.
__global__ __launch_bounds__(256) void conv_main_kernel(const unsigned short* __restrict__ xt,
                                                        const unsigned short* __restrict__ wt,
                                                        const float* __restrict__ bias,
                                                        float* __restrict__ out) {
    int b = blockIdx.x;
    int h = b & 31, d = (b >> 5) & 7, t = (b >> 8) & 7, n = b >> 11;
    int tid  = threadIdx.x;
    int wv   = tid >> 6;
    int lane = tid & 63;
    int w0  = (wv & 1) * 16;
    int oc0 = (wv >> 1) * 16;
    int row16 = lane & 15;
    int chunk = lane >> 4;
    int icA = (chunk & 1) * 8;
    bool lo = (chunk < 2);

    int abase = ((((n * TP + t) * DP + d) * HP + h) * WP + (w0 + row16)) * IN_C + icA;
    int bbase = (oc0 + row16) * IN_C + icA;

    f32x4 acc = {0.f, 0.f, 0.f, 0.f};

#pragma unroll
    for (int it = 0; it < 41; ++it) {
        const int tA = 2 * it;
        const int tB = 2 * it + 1;
        const int tBa = (tB > 80) ? 80 : tB;   // clamp for A (finite values; B side is 0)
        const int aoffA = tap_off(tA);
        const int aoffB = tap_off(tBa);
        const int boffA = tA * (OUT_C * IN_C);
        const int boffB = tB * (OUT_C * IN_C); // tap 81 exists in wt, zero-filled
        int aoff = lo ? aoffA : aoffB;
        int boff = lo ? boffA : boffB;
        bf16x8 av = *reinterpret_cast<const bf16x8*>(xt + abase + aoff);
        bf16x8 bv = *reinterpret_cast<const bf16x8*>(wt + bbase + boff);
        acc = __builtin_amdgcn_mfma_f32_16x16x32_bf16(av, bv, acc, 0, 0, 0);
    }

    int oc = oc0 + row16;
    float bsv = bias[oc];
    f32x4 r = acc;
    r.x += bsv; r.y += bsv; r.z += bsv; r.w += bsv;

    int wout = w0 + chunk * 4;
    float* dst = out + ((((n * OUT_C + oc) * TT + t) * DD + d) * HH + h) * WW + wout;
    *reinterpret_cast<f32x4*>(dst) = r;
}

extern "C" void kernel_launch(void* const* d_in, const int* in_sizes, int n_in,
                              void* d_out, int out_size, void* d_ws, size_t ws_size,
                              hipStream_t stream) {
    const float* x     = (const float*)d_in[0];
    const float* wsrc  = (const float*)d_in[1];
    const float* bias  = (const float*)d_in[2];
    float* out         = (float*)d_out;

    unsigned short* xt = (unsigned short*)d_ws;
    unsigned short* wt = xt + XT_ELEMS;

    // zero the padded input (borders must be 0); interior overwritten by xpose
    hipMemsetAsync(d_ws, 0, (size_t)XT_ELEMS * sizeof(unsigned short), stream);

    xpose_kernel<<<NB * TT * DD * HH, 512, 0, stream>>>(x, xt);
    wxform_kernel<<<(WT_ELEMS + 255) / 256, 256, 0, stream>>>(wsrc, wt);
    conv_main_kernel<<<NB * TT * DD * HH, 256, 0, stream>>>(xt, wt, bias, out);
}

// Round 3
// 35.013 us; speedup vs baseline: 1.7517x; 1.7517x over previous
//
#include <hip/hip_runtime.h>

// ---- problem constants ----
#define IN_C  16
#define OUT_C 32
#define NB 2
#define TT 8
#define DD 8
#define HH 32
#define WW 32
#define TP 10
#define DP 10
#define HP 34
#define WPAD 34

// xt layout: [n][tp][dp][hp][icblk(2)][w(34)][ic8] bf16 ; row = 2*34*8 elems = 1088 B
#define XT_ROW_B  1088
#define XT_ELEMS  (NB*TP*DP*HP*2*WPAD*8)     // 3,699,200 bf16 = 7,398,400 B
// wt layout: [tap(82)][icblk(2)][oc(32)][ic8] bf16 ; per-tap = 1024 B (tap 81 zeroed)
#define WT_ELEMS  (82*2*OUT_C*8)             // 41,984 bf16

// LDS A slab stride: 768 lines x 16B (680 used, 88 junk pad so ALL staging
// calls are full-wave -- no partially-active wave ever issues global_load_lds)
#define A_SLAB_B 12288

typedef __bf16 bf16x8 __attribute__((ext_vector_type(8)));
typedef float  f32x4  __attribute__((ext_vector_type(4)));

__device__ __forceinline__ unsigned short f2bf(float f) {
    unsigned int u = __builtin_bit_cast(unsigned int, f);
    u += 0x7fffu + ((u >> 16) & 1u);       // RNE
    return (unsigned short)(u >> 16);
}

__device__ __forceinline__ void gload16(const void* g, void* l) {
    __builtin_amdgcn_global_load_lds(
        (const __attribute__((address_space(1))) unsigned int*)g,
        (__attribute__((address_space(3))) unsigned int*)l, 16, 0, 0);
}

// ---------------- x -> bf16, padded, layout [n][tp][dp][hp][icblk][w][8] ----------------
__global__ __launch_bounds__(512) void xpose_kernel(const float* __restrict__ x,
                                                    unsigned short* __restrict__ xt) {
    __shared__ unsigned short ls[WW * IN_C];
    int b = blockIdx.x;
    int h = b & 31, d = (b >> 5) & 7, t = (b >> 8) & 7, n = b >> 11;
    int tid = threadIdx.x;
    int c = tid >> 5, w = tid & 31;
    float v = x[((((size_t)(n * IN_C + c) * TT + t) * DD + d) * HH + h) * WW + w];
    ls[w * IN_C + c] = f2bf(v);
    __syncthreads();
    if (tid < 256) {
        int blk = tid >> 7;             // icblk
        int rem = tid & 127;
        int w2 = rem >> 2, cp = rem & 3;
        int c0 = blk * 8 + cp * 2;
        unsigned int val = (unsigned int)ls[w2 * 16 + c0] |
                           ((unsigned int)ls[w2 * 16 + c0 + 1] << 16);
        unsigned char* row = (unsigned char*)xt +
            (size_t)((((n * TP) + t + 1) * DP + d + 1) * HP + h + 1) * XT_ROW_B;
        *(unsigned int*)(row + blk * 544 + (w2 + 1) * 16 + cp * 4) = val;
    }
}

// ---------------- weight -> wt[82][icblk][oc][8] bf16 (tap 81 zeroed) ----------------
__global__ void wxform_kernel(const float* __restrict__ wsrc,
                              unsigned short* __restrict__ wt) {
    int idx = blockIdx.x * blockDim.x + threadIdx.x;
    if (idx >= WT_ELEMS) return;
    int tap = idx >> 9;
    int r = idx & 511;
    int icblk = r >> 8, oc = (r >> 3) & 31, i8 = r & 7;
    int ic = icblk * 8 + i8;
    float v = (tap < 81) ? wsrc[(oc * IN_C + ic) * 81 + tap] : 0.0f;
    wt[idx] = f2bf(v);
}

// ---------------- main: LDS-staged implicit GEMM ----------------
// block = 8 waves, tile = 8 h-rows x 32 w x 32 oc; wave = 1 h-row, 2x2 frags.
// As[kd(3)][slab 768x16B] : rows [hh(10)][icblk(2)][w(34)][8], rows 10..12 junk pad
// Bs[tapl(28)][icblk(2)][oc(32)][8] = 28,672 B  (tapl 27 = zeros)
__global__ __launch_bounds__(512, 4) void conv_main_kernel(const unsigned short* __restrict__ xt,
                                                           const unsigned short* __restrict__ wt,
                                                           const float* __restrict__ bias,
                                                           float* __restrict__ out) {
    __shared__ __align__(16) unsigned char As[3 * A_SLAB_B];   // 36,864 B
    __shared__ __align__(16) unsigned char Bs[28672];

    int b = blockIdx.x;
    int hb = b & 3, d = (b >> 2) & 7, t = (b >> 5) & 7, n = b >> 8;
    int h0 = hb * 8;
    int tid  = threadIdx.x;
    int wv   = tid >> 6;
    int lane = tid & 63;
    int l16  = lane & 15;
    int chunk = lane >> 4;
    int icblk = chunk & 1;
    bool lo = (chunk < 2);

    // byte bases into LDS for this lane
    int Abase = wv * 1088 + icblk * 544 + l16 * 16;   // + tap offset + f*256
    int Bbase = icblk * 512 + l16 * 16;               // + tapl*1024 + nn*256

    f32x4 acc00 = {0.f,0.f,0.f,0.f}, acc01 = {0.f,0.f,0.f,0.f};
    f32x4 acc10 = {0.f,0.f,0.f,0.f}, acc11 = {0.f,0.f,0.f,0.f};

    for (int kt = 0; kt < 3; ++kt) {
        __syncthreads();   // previous compute done before restage
        // ---- stage A: 3 slabs (kd). 512 lines full-block + 256 lines by
        // waves 0..3 (wave-uniform predicate; lines 680..767 are junk pad) ----
        for (int kd = 0; kd < 3; ++kd) {
            const unsigned char* src = (const unsigned char*)xt +
                (size_t)(((n * TP + t + kt) * DP + d + kd) * HP + h0) * XT_ROW_B;
            unsigned char* dst = As + kd * A_SLAB_B;
            gload16(src + tid * 16, dst + tid * 16);
            if (tid < 256) gload16(src + (tid + 512) * 16, dst + (tid + 512) * 16);
        }
        // ---- stage B: 1792 x 16B (i=3 tail: tid<256, wave-uniform) ----
        for (int i = 0; i < 4; ++i) {
            int s = tid + i * 512;
            if (s < 1792) {
                int tapl = s >> 6, off = s & 63;
                int gtap = (tapl < 27) ? (kt * 27 + tapl) : 81;
                gload16((const unsigned char*)wt + (size_t)gtap * 1024 + off * 16,
                        Bs + s * 16);
            }
        }
        asm volatile("s_waitcnt vmcnt(0)" ::: "memory");
        __syncthreads();

        // ---- compute: 14 tap-pairs, 4 MFMA each ----
#pragma unroll
        for (int p = 0; p < 14; ++p) {
            const int ta  = 2 * p;
            const int tbB = 2 * p + 1;
            const int tbA = (tbB < 27) ? tbB : 26;   // A-side clamp (B side is zero)
            const int offA = (ta  / 9) * A_SLAB_B + ((ta  % 9) / 3) * 1088 + (ta  % 3) * 16;
            const int offB = (tbA / 9) * A_SLAB_B + ((tbA % 9) / 3) * 1088 + (tbA % 3) * 16;
            int aoff = Abase + (lo ? offA : offB);
            int boff = Bbase + (lo ? ta * 1024 : tbB * 1024);
            bf16x8 a0 = *(const bf16x8*)(As + aoff);
            bf16x8 a1 = *(const bf16x8*)(As + aoff + 256);
            bf16x8 b0 = *(const bf16x8*)(Bs + boff);
            bf16x8 b1 = *(const bf16x8*)(Bs + boff + 256);
            acc00 = __builtin_amdgcn_mfma_f32_16x16x32_bf16(a0, b0, acc00, 0, 0, 0);
            acc01 = __builtin_amdgcn_mfma_f32_16x16x32_bf16(a0, b1, acc01, 0, 0, 0);
            acc10 = __builtin_amdgcn_mfma_f32_16x16x32_bf16(a1, b0, acc10, 0, 0, 0);
            acc11 = __builtin_amdgcn_mfma_f32_16x16x32_bf16(a1, b1, acc11, 0, 0, 0);
        }
    }

    // ---- epilogue ----
    int h = h0 + wv;
    float bs0 = bias[l16], bs1 = bias[16 + l16];
    int wb = chunk * 4;
    float* orow0 = out + ((((size_t)(n * OUT_C + l16) * TT + t) * DD + d) * HH + h) * WW;
    float* orow1 = orow0 + (size_t)16 * TT * DD * HH * WW;
    f32x4 r;
    r = acc00; r.x += bs0; r.y += bs0; r.z += bs0; r.w += bs0;
    *(f32x4*)(orow0 + wb) = r;
    r = acc10; r.x += bs0; r.y += bs0; r.z += bs0; r.w += bs0;
    *(f32x4*)(orow0 + 16 + wb) = r;
    r = acc01; r.x += bs1; r.y += bs1; r.z += bs1; r.w += bs1;
    *(f32x4*)(orow1 + wb) = r;
    r = acc11; r.x += bs1; r.y += bs1; r.z += bs1; r.w += bs1;
    *(f32x4*)(orow1 + 16 + wb) = r;
}

extern "C" void kernel_launch(void* const* d_in, const int* in_sizes, int n_in,
                              void* d_out, int out_size, void* d_ws, size_t ws_size,
                              hipStream_t stream) {
    const float* x    = (const float*)d_in[0];
    const float* wsrc = (const float*)d_in[1];
    const float* bias = (const float*)d_in[2];
    float* out        = (float*)d_out;

    unsigned short* xt = (unsigned short*)d_ws;
    unsigned short* wt = xt + XT_ELEMS;

    hipMemsetAsync(d_ws, 0, (size_t)XT_ELEMS * sizeof(unsigned short), stream);

    xpose_kernel<<<NB * TT * DD * HH, 512, 0, stream>>>(x, xt);
    wxform_kernel<<<WT_ELEMS / 256, 256, 0, stream>>>(wsrc, wt);
    conv_main_kernel<<<NB * TT * DD * 4, 512, 0, stream>>>(xt, wt, bias, out);
}

// Round 4
// 34.167 us; speedup vs baseline: 1.7951x; 1.0248x over previous
//
#include <hip/hip_runtime.h>

// ---- problem constants ----
#define IN_C  16
#define OUT_C 32
#define NB 2
#define TT 8
#define DD 8
#define HH 32
#define WW 32
#define TP 10
#define DP 10
#define HP 34
#define WPAD 34

// xt layout: [n][tp][dp][hp][icblk(2)][w(34)][ic8] bf16 ; row = 2*34*8 elems = 1088 B
#define XT_ROW_B  1088
#define XT_ELEMS  (NB*TP*DP*HP*2*WPAD*8)     // 3,699,200 bf16 = 7,398,400 B
// wt layout: [tap(82)][icblk(2)][oc(32)][ic8] bf16 ; per-tap = 1024 B (tap 81 zeroed)
#define WT_ELEMS  (82*2*OUT_C*8)             // 41,984 bf16

// LDS A slab stride: 768 lines x 16B (680 used; pad so all staging is full-wave)
#define A_SLAB_B 12288

typedef __bf16 bf16x8 __attribute__((ext_vector_type(8)));
typedef float  f32x4  __attribute__((ext_vector_type(4)));

__device__ __forceinline__ unsigned short f2bf(float f) {
    unsigned int u = __builtin_bit_cast(unsigned int, f);
    u += 0x7fffu + ((u >> 16) & 1u);       // RNE
    return (unsigned short)(u >> 16);
}

__device__ __forceinline__ void gload16(const void* g, void* l) {
    __builtin_amdgcn_global_load_lds(
        (const __attribute__((address_space(1))) unsigned int*)g,
        (__attribute__((address_space(3))) unsigned int*)l, 16, 0, 0);
}

// ---------------- zero-fill xt (replaces pathologically slow rocclr fill) ----------------
__global__ __launch_bounds__(256) void fill_zero_kernel(f32x4* __restrict__ p, int n16) {
    int i = blockIdx.x * blockDim.x + threadIdx.x;
    if (i < n16) {
        f32x4 z = {0.f, 0.f, 0.f, 0.f};
        p[i] = z;
    }
}

// ---------------- x -> bf16, padded, layout [n][tp][dp][hp][icblk][w][8] ----------------
__global__ __launch_bounds__(512) void xpose_kernel(const float* __restrict__ x,
                                                    unsigned short* __restrict__ xt) {
    __shared__ unsigned short ls[WW * IN_C];
    int b = blockIdx.x;
    int h = b & 31, d = (b >> 5) & 7, t = (b >> 8) & 7, n = b >> 11;
    int tid = threadIdx.x;
    int c = tid >> 5, w = tid & 31;
    float v = x[((((size_t)(n * IN_C + c) * TT + t) * DD + d) * HH + h) * WW + w];
    ls[w * IN_C + c] = f2bf(v);
    __syncthreads();
    if (tid < 256) {
        int blk = tid >> 7;             // icblk
        int rem = tid & 127;
        int w2 = rem >> 2, cp = rem & 3;
        int c0 = blk * 8 + cp * 2;
        unsigned int val = (unsigned int)ls[w2 * 16 + c0] |
                           ((unsigned int)ls[w2 * 16 + c0 + 1] << 16);
        unsigned char* row = (unsigned char*)xt +
            (size_t)((((n * TP) + t + 1) * DP + d + 1) * HP + h + 1) * XT_ROW_B;
        *(unsigned int*)(row + blk * 544 + (w2 + 1) * 16 + cp * 4) = val;
    }
}

// ---------------- weight -> wt[82][icblk][oc][8] bf16 (tap 81 zeroed) ----------------
__global__ void wxform_kernel(const float* __restrict__ wsrc,
                              unsigned short* __restrict__ wt) {
    int idx = blockIdx.x * blockDim.x + threadIdx.x;
    if (idx >= WT_ELEMS) return;
    int tap = idx >> 9;
    int r = idx & 511;
    int icblk = r >> 8, oc = (r >> 3) & 31, i8 = r & 7;
    int ic = icblk * 8 + i8;
    float v = (tap < 81) ? wsrc[(oc * IN_C + ic) * 81 + tap] : 0.0f;
    wt[idx] = f2bf(v);
}

// ---------------- main: LDS-staged implicit GEMM, 4 waves, M_rep=4 x N_rep=2 ----------------
// block = 4 waves (256 thr), tile = 8 h-rows x 32 w x 32 oc; wave = 2 h-rows.
// As[kd(3)][slab 768x16B] : rows [hh(10)][icblk(2)][w(34)][8], rows 10..12 junk pad
// Bs[tapl(28)][icblk(2)][oc(32)][8] = 28,672 B  (tapl 27 = zeros)
__global__ __launch_bounds__(256, 2) void conv_main_kernel(const unsigned short* __restrict__ xt,
                                                           const unsigned short* __restrict__ wt,
                                                           const float* __restrict__ bias,
                                                           float* __restrict__ out) {
    __shared__ __align__(16) unsigned char As[3 * A_SLAB_B];   // 36,864 B
    __shared__ __align__(16) unsigned char Bs[28672];

    int b = blockIdx.x;
    int hb = b & 3, d = (b >> 2) & 7, t = (b >> 5) & 7, n = b >> 8;
    int h0 = hb * 8;
    int tid  = threadIdx.x;
    int wv   = tid >> 6;            // 0..3, owns h-rows 2wv, 2wv+1
    int lane = tid & 63;
    int l16  = lane & 15;
    int chunk = lane >> 4;
    int icblk = chunk & 1;
    bool lo = (chunk < 2);

    f32x4 acc[4][2];
#pragma unroll
    for (int m = 0; m < 4; ++m)
#pragma unroll
        for (int nn = 0; nn < 2; ++nn)
            acc[m][nn] = (f32x4){0.f, 0.f, 0.f, 0.f};

    for (int kt = 0; kt < 3; ++kt) {
        __syncthreads();   // previous compute done before restage
        // ---- stage A: 3 slabs (kd), 768 lines each, 256 thr -> 3 full-wave rounds ----
        for (int kd = 0; kd < 3; ++kd) {
            const unsigned char* src = (const unsigned char*)xt +
                (size_t)(((n * TP + t + kt) * DP + d + kd) * HP + h0) * XT_ROW_B;
            unsigned char* dst = As + kd * A_SLAB_B;
            gload16(src + tid * 16,          dst + tid * 16);
            gload16(src + (tid + 256) * 16,  dst + (tid + 256) * 16);
            gload16(src + (tid + 512) * 16,  dst + (tid + 512) * 16);
        }
        // ---- stage B: 1792 lines = 7 full-wave rounds ----
#pragma unroll
        for (int i = 0; i < 7; ++i) {
            int s = tid + i * 256;
            int tapl = s >> 6, off = s & 63;
            int gtap = (tapl < 27) ? (kt * 27 + tapl) : 81;
            gload16((const unsigned char*)wt + (size_t)gtap * 1024 + off * 16,
                    Bs + s * 16);
        }
        asm volatile("s_waitcnt vmcnt(0)" ::: "memory");
        __syncthreads();

        // ---- compute: 14 tap-pairs, 8 MFMA each (4 A-frags x 2 B-frags) ----
#pragma unroll
        for (int p = 0; p < 14; ++p) {
            const int ta  = 2 * p;
            const int tbB = 2 * p + 1;
            const int tbA = (tbB < 27) ? tbB : 26;   // A-side clamp (B side is zero)
            const int offA = (ta  / 9) * A_SLAB_B + ((ta  % 9) / 3) * 1088 + (ta  % 3) * 16;
            const int offB = (tbA / 9) * A_SLAB_B + ((tbA % 9) / 3) * 1088 + (tbA % 3) * 16;
            int aoff = (lo ? offA : offB) + icblk * 544 + l16 * 16;
            int boff = (lo ? ta * 1024 : tbB * 1024) + icblk * 512 + l16 * 16;
            bf16x8 b0 = *(const bf16x8*)(Bs + boff);
            bf16x8 b1 = *(const bf16x8*)(Bs + boff + 256);
#pragma unroll
            for (int m = 0; m < 4; ++m) {
                int am = aoff + (2 * wv + (m >> 1)) * 1088 + (m & 1) * 256;
                bf16x8 av = *(const bf16x8*)(As + am);
                acc[m][0] = __builtin_amdgcn_mfma_f32_16x16x32_bf16(av, b0, acc[m][0], 0, 0, 0);
                acc[m][1] = __builtin_amdgcn_mfma_f32_16x16x32_bf16(av, b1, acc[m][1], 0, 0, 0);
            }
        }
    }

    // ---- epilogue ----
    float bs[2] = { bias[l16], bias[16 + l16] };
    int wb = chunk * 4;
#pragma unroll
    for (int m = 0; m < 4; ++m) {
        int h = h0 + 2 * wv + (m >> 1);
        int wout = 16 * (m & 1) + wb;
#pragma unroll
        for (int nn = 0; nn < 2; ++nn) {
            int oc = 16 * nn + l16;
            float* dst = out + ((((size_t)(n * OUT_C + oc) * TT + t) * DD + d) * HH + h) * WW + wout;
            f32x4 r = acc[m][nn];
            r.x += bs[nn]; r.y += bs[nn]; r.z += bs[nn]; r.w += bs[nn];
            *(f32x4*)dst = r;
        }
    }
}

extern "C" void kernel_launch(void* const* d_in, const int* in_sizes, int n_in,
                              void* d_out, int out_size, void* d_ws, size_t ws_size,
                              hipStream_t stream) {
    const float* x    = (const float*)d_in[0];
    const float* wsrc = (const float*)d_in[1];
    const float* bias = (const float*)d_in[2];
    float* out        = (float*)d_out;

    unsigned short* xt = (unsigned short*)d_ws;
    unsigned short* wt = xt + XT_ELEMS;

    const int n16 = (XT_ELEMS * 2) / 16;     // 462,400 16B lines
    fill_zero_kernel<<<(n16 + 255) / 256, 256, 0, stream>>>((f32x4*)d_ws, n16);

    xpose_kernel<<<NB * TT * DD * HH, 512, 0, stream>>>(x, xt);
    wxform_kernel<<<WT_ELEMS / 256, 256, 0, stream>>>(wsrc, wt);
    conv_main_kernel<<<NB * TT * DD * 4, 256, 0, stream>>>(xt, wt, bias, out);
}